// Round 8
// baseline (55.423 us; speedup 1.0000x reference)
//
#include <hip/hip_runtime.h>

#define TDIM 4096
#define SBAR() __builtin_amdgcn_sched_barrier(0)

// frame layout: f[0..8]=R (row major), f[9..11]=pos, f[12..15]=parent raw quat
__device__ __forceinline__ void fk_step(float* __restrict__ f,
                                        const float* __restrict__ q,
                                        float o0, float o1, float o2) {
  const float pw = f[12], px = f[13], py = f[14], pz = f[15];
  // loc = conj(parent_q) * q
  float lw = pw*q[0] + px*q[1] + py*q[2] + pz*q[3];
  float lx = pw*q[1] - px*q[0] - py*q[3] + pz*q[2];
  float ly = pw*q[2] + px*q[3] - py*q[0] - pz*q[1];
  float lz = pw*q[3] - px*q[2] + py*q[1] - pz*q[0];
  float n2 = lw*lw + lx*lx + ly*ly + lz*lz;
  float inv = rsqrtf(fmaxf(n2, 1e-16f));
  lw *= inv; lx *= inv; ly *= inv; lz *= inv;
  float xx = lx*lx, yy = ly*ly, zz = lz*lz;
  float xy = lx*ly, xz = lx*lz, yz = ly*lz;
  float wx = lw*lx, wy = lw*ly, wz = lw*lz;
  float m0 = 1.0f-2.0f*(yy+zz), m1 = 2.0f*(xy-wz),      m2 = 2.0f*(xz+wy);
  float m3 = 2.0f*(xy+wz),      m4 = 1.0f-2.0f*(xx+zz), m5 = 2.0f*(yz-wx);
  float m6 = 2.0f*(xz-wy),      m7 = 2.0f*(yz+wx),      m8 = 1.0f-2.0f*(xx+yy);
  f[9]  += f[0]*o0 + f[1]*o1 + f[2]*o2;
  f[10] += f[3]*o0 + f[4]*o1 + f[5]*o2;
  f[11] += f[6]*o0 + f[7]*o1 + f[8]*o2;
  float r0 = f[0]*m0 + f[1]*m3 + f[2]*m6;
  float r1 = f[0]*m1 + f[1]*m4 + f[2]*m7;
  float r2 = f[0]*m2 + f[1]*m5 + f[2]*m8;
  float r3 = f[3]*m0 + f[4]*m3 + f[5]*m6;
  float r4 = f[3]*m1 + f[4]*m4 + f[5]*m7;
  float r5 = f[3]*m2 + f[4]*m5 + f[5]*m8;
  float r6 = f[6]*m0 + f[7]*m3 + f[8]*m6;
  float r7 = f[6]*m1 + f[7]*m4 + f[8]*m7;
  float r8 = f[6]*m2 + f[7]*m5 + f[8]*m8;
  f[0]=r0; f[1]=r1; f[2]=r2; f[3]=r3; f[4]=r4; f[5]=r5; f[6]=r6; f[7]=r7; f[8]=r8;
  f[12]=q[0]; f[13]=q[1]; f[14]=q[2]; f[15]=q[3];
}

// Lane-split streams: lanes 0-20 ik, 21-41 dec, 42-62 tgt (same 21 (b,t) groups),
// lane 63 duplicates tgt g=20 and contributes 0. Cross-stream diff via __shfl
// (intra-wave, no barriers). All lanes run identical straight-line code.
__global__ __launch_bounds__(256) void fk_loss_kernel(
    const float* __restrict__ ik,   // (32, 168, 4096)
    const float* __restrict__ dec,  // (32, 176, 4096)
    const float* __restrict__ tgt,  // (32, 176, 4096)
    const float* __restrict__ mean, // (176,)
    const float* __restrict__ stdv, // (176,)
    const float* __restrict__ offs, // (22, 3)
    float* __restrict__ out)
{
  __shared__ float s_mean[176];
  __shared__ float s_std[176];
  __shared__ float s_wsum[4];
  const int tid = threadIdx.x;
  for (int i = tid; i < 176; i += 256) { s_mean[i] = mean[i]; s_std[i] = stdv[i]; }
  __syncthreads();

  const int lane = tid & 63, wid = tid >> 6;
  int s = lane / 21;                 // 0,1,2  (lane 63 -> 3)
  int g = lane - s * 21;             // 0..20
  s = (lane == 63) ? 2 : s;
  g = (lane == 63) ? 20 : g;

  int gidx = blockIdx.x * 84 + wid * 21 + g;   // group = (b,t) pair
  const bool valid = gidx < 131072;
  gidx = valid ? gidx : 131071;                // clamp: duplicate work, zero loss
  const int b = gidx >> 12;
  const int t = gidx & 4095;

  const float* __restrict__ tp = tgt + ((size_t)b * 176) * TDIM + t;
  // ik pointer pre-shifted -8 channels so channel index j*8+c works for all roles
  const float* __restrict__ p =
      (s == 0) ? (ik + ((size_t)b * 168) * TDIM + t - (size_t)8 * TDIM)
    : (s == 1) ? (dec + ((size_t)b * 176) * TDIM + t)
    :            tp;

  // partner lanes for the diff pulls (self-pull => d = 0)
  const int pNS = (s == 0 && valid) ? lane + 21 : lane;   // dec partner
  const int pEE = (s == 0 && valid) ? lane + 42 : lane;   // tgt partner

  // root parent quat: identity for ik/dec (set_root), denormed tgt ch0..3 for tgt
  float pq[4];
  {
    float r0 = fmaf(tp[0 * TDIM], s_std[0], s_mean[0]);
    float r1 = fmaf(tp[1 * TDIM], s_std[1], s_mean[1]);
    float r2 = fmaf(tp[2 * TDIM], s_std[2], s_mean[2]);
    float r3 = fmaf(tp[3 * TDIM], s_std[3], s_mean[3]);
    pq[0] = (s == 2) ? r0 : 1.f;
    pq[1] = (s == 2) ? r1 : 0.f;
    pq[2] = (s == 2) ? r2 : 0.f;
    pq[3] = (s == 2) ? r3 : 0.f;
  }

  float see_p = 0.f, see_m = 0.f, srg_p = 0.f, srg_m = 0.f;
  float f[16], sv[16];
  float S0[4], S1[4];

#define LOADJ(buf, j)                                                          \
  { _Pragma("unroll")                                                          \
    for (int c = 0; c < 4; c++) buf[c] = p[((j)*8 + c) * TDIM]; }

#define COMP(buf, j)                                                           \
  { float q[4];                                                                \
    _Pragma("unroll")                                                          \
    for (int c = 0; c < 4; c++)                                                \
      q[c] = fmaf(buf[c], s_std[(j)*8 + c], s_mean[(j)*8 + c]);                \
    fk_step(f, q, offs[(j)*3], offs[(j)*3 + 1], offs[(j)*3 + 2]); }

// diff via intra-wave shuffle: ik lanes pull partner frame; others pull self (d=0)
#define DIFF(PL, accp, accm)                                                   \
  { _Pragma("unroll")                                                          \
    for (int c = 0; c < 9; c++) { float d = __shfl(f[c], PL, 64) - f[c];       \
                                  accm = fmaf(d, d, accm); }                   \
    _Pragma("unroll")                                                          \
    for (int c = 0; c < 3; c++) { float d = __shfl(f[9 + c], PL, 64) - f[9 + c]; \
                                  accp = fmaf(d, d, accp); } }

#define DIFF_NS() DIFF(pNS, srg_p, srg_m)
#define DIFF_EE() DIFF(pEE, see_p, see_m)

#define RESET()                                                                \
  { _Pragma("unroll")                                                          \
    for (int c = 0; c < 16; c++) f[c] = 0.f;                                   \
    f[0] = f[4] = f[8] = 1.f;                                                  \
    f[12] = pq[0]; f[13] = pq[1]; f[14] = pq[2]; f[15] = pq[3]; }

#define SAVE()                                                                 \
  { _Pragma("unroll")                                                          \
    for (int c = 0; c < 16; c++) sv[c] = f[c]; }

#define RESTORE()                                                              \
  { _Pragma("unroll")                                                          \
    for (int c = 0; c < 16; c++) f[c] = sv[c]; }

  // ---- ladder: depth-1 prefetch, one stream per lane ----
  LOADJ(S0, 1);
  SBAR();
  RESET();
  LOADJ(S1, 2);  COMP(S0, 1);  DIFF_NS(); SBAR();
  LOADJ(S0, 3);  COMP(S1, 2);  DIFF_NS(); SBAR();
  LOADJ(S1, 4);  COMP(S0, 3);  DIFF_NS(); SBAR();
  LOADJ(S0, 5);  COMP(S1, 4);  DIFF_EE(); RESET(); SBAR();
  LOADJ(S1, 6);  COMP(S0, 5);  DIFF_NS(); SBAR();
  LOADJ(S0, 7);  COMP(S1, 6);  DIFF_NS(); SBAR();
  LOADJ(S1, 8);  COMP(S0, 7);  DIFF_NS(); SBAR();
  LOADJ(S0, 9);  COMP(S1, 8);  DIFF_EE(); RESET(); SBAR();
  LOADJ(S1, 10); COMP(S0, 9);  DIFF_NS(); SBAR();
  LOADJ(S0, 11); COMP(S1, 10); DIFF_NS(); SBAR();
  LOADJ(S1, 12); COMP(S0, 11); DIFF_NS(); SAVE(); SBAR();
  LOADJ(S0, 13); COMP(S1, 12); DIFF_NS(); SBAR();
  LOADJ(S1, 14); COMP(S0, 13); DIFF_EE(); RESTORE(); SBAR();
  LOADJ(S0, 15); COMP(S1, 14); DIFF_NS(); SBAR();
  LOADJ(S1, 16); COMP(S0, 15); DIFF_NS(); SBAR();
  LOADJ(S0, 17); COMP(S1, 16); DIFF_NS(); SBAR();
  LOADJ(S1, 18); COMP(S0, 17); DIFF_EE(); RESTORE(); SBAR();
  LOADJ(S0, 19); COMP(S1, 18); DIFF_NS(); SBAR();
  LOADJ(S1, 20); COMP(S0, 19); DIFF_NS(); SBAR();
  LOADJ(S0, 21); COMP(S1, 20); DIFF_NS(); SBAR();
  COMP(S0, 21); DIFF_EE();

#undef LOADJ
#undef COMP
#undef DIFF
#undef DIFF_NS
#undef DIFF_EE
#undef RESET
#undef SAVE
#undef RESTORE

  // weights: see_p/(BT*15) + see_m/(BT*45) + 0.1*(srg_p/(BT*48) + srg_m/(BT*144))
  const float W1 = 1.0f / 1966080.0f;
  const float W2 = 1.0f / 5898240.0f;
  const float W3 = 0.1f / 6291456.0f;
  const float W4 = 0.1f / 18874368.0f;
  float val = see_p * W1 + see_m * W2 + srg_p * W3 + srg_m * W4;

  #pragma unroll
  for (int o = 32; o > 0; o >>= 1) val += __shfl_down(val, o, 64);
  if ((tid & 63) == 0) s_wsum[wid] = val;
  __syncthreads();
  if (tid == 0) atomicAdd(out, s_wsum[0] + s_wsum[1] + s_wsum[2] + s_wsum[3]);
}

extern "C" void kernel_launch(void* const* d_in, const int* in_sizes, int n_in,
                              void* d_out, int out_size, void* d_ws, size_t ws_size,
                              hipStream_t stream) {
  const float* ik   = (const float*)d_in[1];
  const float* dec  = (const float*)d_in[2];
  const float* tgt  = (const float*)d_in[3];
  const float* mean = (const float*)d_in[4];
  const float* stdv = (const float*)d_in[5];
  const float* offs = (const float*)d_in[6];
  float* out = (float*)d_out;

  hipMemsetAsync(out, 0, sizeof(float), stream);
  // 131072 (b,t) groups, 84 groups per 256-thread block (21 per wave)
  fk_loss_kernel<<<dim3(1561), dim3(256), 0, stream>>>(ik, dec, tgt, mean, stdv, offs, out);
}

// Round 9
// 35.416 us; speedup vs baseline: 1.5649x; 1.5649x over previous
//
#include <hip/hip_runtime.h>
#include <stdint.h>

#define TDIM 4096
#define SBAR() __builtin_amdgcn_sched_barrier(0)
#define WAITV3() asm volatile("s_waitcnt vmcnt(3)" ::: "memory")
#define WAITV0() asm volatile("s_waitcnt vmcnt(0)" ::: "memory")

// async global->LDS, 16B per lane: lane i writes LDS base + i*16
__device__ __forceinline__ void gll16(const float* gp, const float* lp) {
  __builtin_amdgcn_global_load_lds(
      (const __attribute__((address_space(1))) uint32_t*)(uintptr_t)gp,
      (__attribute__((address_space(3))) uint32_t*)(uintptr_t)lp,
      16, 0, 0);
}

// frame layout: f[0..8]=R (row major), f[9..11]=pos, f[12..15]=parent raw quat
__device__ __forceinline__ void fk_step(float* __restrict__ f,
                                        const float* __restrict__ q,
                                        float o0, float o1, float o2) {
  const float pw = f[12], px = f[13], py = f[14], pz = f[15];
  float lw = pw*q[0] + px*q[1] + py*q[2] + pz*q[3];
  float lx = pw*q[1] - px*q[0] - py*q[3] + pz*q[2];
  float ly = pw*q[2] + px*q[3] - py*q[0] - pz*q[1];
  float lz = pw*q[3] - px*q[2] + py*q[1] - pz*q[0];
  float n2 = lw*lw + lx*lx + ly*ly + lz*lz;
  float inv = rsqrtf(fmaxf(n2, 1e-16f));
  lw *= inv; lx *= inv; ly *= inv; lz *= inv;
  float xx = lx*lx, yy = ly*ly, zz = lz*lz;
  float xy = lx*ly, xz = lx*lz, yz = ly*lz;
  float wx = lw*lx, wy = lw*ly, wz = lw*lz;
  float m0 = 1.0f-2.0f*(yy+zz), m1 = 2.0f*(xy-wz),      m2 = 2.0f*(xz+wy);
  float m3 = 2.0f*(xy+wz),      m4 = 1.0f-2.0f*(xx+zz), m5 = 2.0f*(yz-wx);
  float m6 = 2.0f*(xz-wy),      m7 = 2.0f*(yz+wx),      m8 = 1.0f-2.0f*(xx+yy);
  f[9]  += f[0]*o0 + f[1]*o1 + f[2]*o2;
  f[10] += f[3]*o0 + f[4]*o1 + f[5]*o2;
  f[11] += f[6]*o0 + f[7]*o1 + f[8]*o2;
  float r0 = f[0]*m0 + f[1]*m3 + f[2]*m6;
  float r1 = f[0]*m1 + f[1]*m4 + f[2]*m7;
  float r2 = f[0]*m2 + f[1]*m5 + f[2]*m8;
  float r3 = f[3]*m0 + f[4]*m3 + f[5]*m6;
  float r4 = f[3]*m1 + f[4]*m4 + f[5]*m7;
  float r5 = f[3]*m2 + f[4]*m5 + f[5]*m8;
  float r6 = f[6]*m0 + f[7]*m3 + f[8]*m6;
  float r7 = f[6]*m1 + f[7]*m4 + f[8]*m7;
  float r8 = f[6]*m2 + f[7]*m5 + f[8]*m8;
  f[0]=r0; f[1]=r1; f[2]=r2; f[3]=r3; f[4]=r4; f[5]=r5; f[6]=r6; f[7]=r7; f[8]=r8;
  f[12]=q[0]; f[13]=q[1]; f[14]=q[2]; f[15]=q[3];
}

// Block = 256 threads (4 waves) covering 256 consecutive t of one batch b.
// Staging: per joint, 12 channels x 1KB via global_load_lds width-16
// (3 per wave), triple-buffered; one raw s_barrier + counted vmcnt(3)/round.
// Compute: per-thread 3-stream FK (proven R2 ladder), LDS reads conflict-free.
__global__ __launch_bounds__(256) void fk_loss_kernel(
    const float* __restrict__ ik,   // (32, 168, 4096)
    const float* __restrict__ dec,  // (32, 176, 4096)
    const float* __restrict__ tgt,  // (32, 176, 4096)
    const float* __restrict__ mean, // (176,)
    const float* __restrict__ stdv, // (176,)
    const float* __restrict__ offs, // (22, 3)
    float* __restrict__ out)
{
  __shared__ float s_mean[176];
  __shared__ float s_std[176];
  __shared__ float buf[3][12][256];   // [parity][slot][t_local]
  __shared__ float s_wsum[4];
  const int tid = threadIdx.x;
  for (int i = tid; i < 176; i += 256) { s_mean[i] = mean[i]; s_std[i] = stdv[i]; }
  __syncthreads();

  const int lane = tid & 63;
  const int wid  = tid >> 6;          // 0..3
  const int s0   = wid * 3;           // this wave's first slot (slots 0..11)
  const int b  = blockIdx.x >> 4;     // 16 blocks per batch (4096/256)
  const int t0 = (blockIdx.x & 15) * 256;

  // per-wave channel pointers at joint 1 (slot -> stream/channel):
  // slot s<4: ik ch (j-1)*8+s ; 4<=s<8: dec ch j*8+(s-4)=s+4 ; s>=8: tgt ch j*8+(s-8)=s
  const float* gpa[3];
  #pragma unroll
  for (int k = 0; k < 3; k++) {
    const int s = s0 + k;
    const float* q;
    if (s < 4)      q = ik  + (size_t)b * 168 * TDIM + (size_t)s       * TDIM;
    else if (s < 8) q = dec + (size_t)b * 176 * TDIM + (size_t)(s + 4) * TDIM;
    else            q = tgt + (size_t)b * 176 * TDIM + (size_t)s       * TDIM;
    gpa[k] = q + t0 + lane * 4;
  }

  // root tgt quat (denormed tgt channels 0..3 at this thread's t)
  const float* tp = tgt + (size_t)b * 176 * TDIM + t0 + tid;
  float rq[4];
  #pragma unroll
  for (int c = 0; c < 4; c++) rq[c] = fmaf(tp[c * TDIM], s_std[c], s_mean[c]);

  float see_p = 0.f, see_m = 0.f, srg_p = 0.f, srg_m = 0.f;
  float fik[16], fdec[16], ftgt[16];
  float sik[16], sdec[16], stgt[16];

#define ISSUE(P)                                                               \
  { gll16(gpa[0], &buf[P][s0 + 0][0]);                                         \
    gll16(gpa[1], &buf[P][s0 + 1][0]);                                         \
    gll16(gpa[2], &buf[P][s0 + 2][0]);                                         \
    gpa[0] += 8 * TDIM; gpa[1] += 8 * TDIM; gpa[2] += 8 * TDIM; }

#define COMPJ(P, j)                                                            \
  { float qi[4], qd[4], qt[4];                                                 \
    _Pragma("unroll")                                                          \
    for (int c = 0; c < 4; c++) {                                              \
      const float sd = s_std[(j)*8 + c], mn = s_mean[(j)*8 + c];               \
      qi[c] = fmaf(buf[P][c][tid],     sd, mn);                                \
      qd[c] = fmaf(buf[P][4 + c][tid], sd, mn);                                \
      qt[c] = fmaf(buf[P][8 + c][tid], sd, mn);                                \
    }                                                                          \
    const float o0 = offs[(j)*3], o1 = offs[(j)*3+1], o2 = offs[(j)*3+2];      \
    fk_step(fik,  qi, o0, o1, o2);                                             \
    fk_step(fdec, qd, o0, o1, o2);                                             \
    fk_step(ftgt, qt, o0, o1, o2); }

#define DIFF_EE()                                                              \
  { _Pragma("unroll")                                                          \
    for (int c = 0; c < 3; c++) { float d = fik[9+c] - ftgt[9+c]; see_p = fmaf(d, d, see_p); } \
    _Pragma("unroll")                                                          \
    for (int c = 0; c < 9; c++) { float d = fik[c]   - ftgt[c];   see_m = fmaf(d, d, see_m); } }

#define DIFF_NS()                                                              \
  { _Pragma("unroll")                                                          \
    for (int c = 0; c < 3; c++) { float d = fdec[9+c] - fik[9+c]; srg_p = fmaf(d, d, srg_p); } \
    _Pragma("unroll")                                                          \
    for (int c = 0; c < 9; c++) { float d = fdec[c]   - fik[c];   srg_m = fmaf(d, d, srg_m); } }

#define RESET()                                                                \
  { _Pragma("unroll")                                                          \
    for (int c = 0; c < 16; c++) { fik[c] = 0.f; fdec[c] = 0.f; ftgt[c] = 0.f; } \
    fik[0]=fik[4]=fik[8]=1.f; fdec[0]=fdec[4]=fdec[8]=1.f; ftgt[0]=ftgt[4]=ftgt[8]=1.f; \
    fik[12]=1.f; fdec[12]=1.f;                                                 \
    ftgt[12]=rq[0]; ftgt[13]=rq[1]; ftgt[14]=rq[2]; ftgt[15]=rq[3]; }

#define SAVE()                                                                 \
  { _Pragma("unroll")                                                          \
    for (int c = 0; c < 16; c++) { sik[c]=fik[c]; sdec[c]=fdec[c]; stgt[c]=ftgt[c]; } }

#define RESTORE()                                                              \
  { _Pragma("unroll")                                                          \
    for (int c = 0; c < 16; c++) { fik[c]=sik[c]; fdec[c]=sdec[c]; stgt[c]; ftgt[c]=stgt[c]; } }

// round r: issue joint r+1 into buf[r%3], counted-wait, barrier, compute joint r
#define ROUND(r)                                                               \
  ISSUE((r) % 3); SBAR(); WAITV3();                                            \
  __builtin_amdgcn_s_barrier(); SBAR();                                        \
  COMPJ((((r) - 1) % 3), r);

  // prologue: joint 1 into buf[0]
  ISSUE(0);
  RESET();

  ROUND(1);  DIFF_NS();
  ROUND(2);  DIFF_NS();
  ROUND(3);  DIFF_NS();
  ROUND(4);  DIFF_EE(); RESET();
  ROUND(5);  DIFF_NS();
  ROUND(6);  DIFF_NS();
  ROUND(7);  DIFF_NS();
  ROUND(8);  DIFF_EE(); RESET();
  ROUND(9);  DIFF_NS();
  ROUND(10); DIFF_NS();
  ROUND(11); DIFF_NS(); SAVE();
  ROUND(12); DIFF_NS();
  ROUND(13); DIFF_EE(); RESTORE();
  ROUND(14); DIFF_NS();
  ROUND(15); DIFF_NS();
  ROUND(16); DIFF_NS();
  ROUND(17); DIFF_EE(); RESTORE();
  ROUND(18); DIFF_NS();
  ROUND(19); DIFF_NS();
  ROUND(20); DIFF_NS();
  // final round: no prefetch
  SBAR(); WAITV0();
  __builtin_amdgcn_s_barrier(); SBAR();
  COMPJ(2, 21); DIFF_EE();

#undef ISSUE
#undef COMPJ
#undef DIFF_EE
#undef DIFF_NS
#undef RESET
#undef SAVE
#undef RESTORE
#undef ROUND

  // weights: see_p/(BT*15) + see_m/(BT*45) + 0.1*(srg_p/(BT*48) + srg_m/(BT*144))
  const float W1 = 1.0f / 1966080.0f;
  const float W2 = 1.0f / 5898240.0f;
  const float W3 = 0.1f / 6291456.0f;
  const float W4 = 0.1f / 18874368.0f;
  float val = see_p * W1 + see_m * W2 + srg_p * W3 + srg_m * W4;

  #pragma unroll
  for (int o = 32; o > 0; o >>= 1) val += __shfl_down(val, o, 64);
  if (lane == 0) s_wsum[wid] = val;
  __syncthreads();
  if (tid == 0) atomicAdd(out, s_wsum[0] + s_wsum[1] + s_wsum[2] + s_wsum[3]);
}

extern "C" void kernel_launch(void* const* d_in, const int* in_sizes, int n_in,
                              void* d_out, int out_size, void* d_ws, size_t ws_size,
                              hipStream_t stream) {
  const float* ik   = (const float*)d_in[1];
  const float* dec  = (const float*)d_in[2];
  const float* tgt  = (const float*)d_in[3];
  const float* mean = (const float*)d_in[4];
  const float* stdv = (const float*)d_in[5];
  const float* offs = (const float*)d_in[6];
  float* out = (float*)d_out;

  hipMemsetAsync(out, 0, sizeof(float), stream);
  fk_loss_kernel<<<dim3(512), dim3(256), 0, stream>>>(ik, dec, tgt, mean, stdv, offs, out);
}